// Round 6
// baseline (180.890 us; speedup 1.0000x reference)
//
#include <hip/hip_runtime.h>
#include <math.h>

#define TAU_CONST 1.0f
#define BLOCK 128                     // 2 waves/block -> 40 KB static LDS/block
#define WPB (BLOCK / 64)              // waves per block
#define NBLOCKS 1024                  // persistent, 4 blocks/CU
#define ROWS_PER_TILE 256             // 64 lanes x 4 rows; 5120 B per input = 5 lds-dma insts

#define INV_PI 0.31830988618f
#define LN2    0.69314718056f

typedef float vfloat4 __attribute__((ext_vector_type(4)));

__device__ __forceinline__ float fast_rcp(float x) { return __builtin_amdgcn_rcpf(x); }
__device__ __forceinline__ float fast_log2(float x) { return __builtin_amdgcn_logf(x); }

// All-HW-instruction row loss (double-angle form; det = a*b exact).
__device__ __forceinline__ float kld_row(const float* p, const float* t) {
    float pw = fminf(fmaxf(p[2], 1e-7f), 1e7f), ph = fminf(fmaxf(p[3], 1e-7f), 1e7f);
    float tw = fminf(fmaxf(t[2], 1e-7f), 1e7f), th = fminf(fmaxf(t[3], 1e-7f), 1e7f);
    float ap = 0.25f * pw * pw, bp = 0.25f * ph * ph;
    float at = 0.25f * tw * tw, bt = 0.25f * th * th;
    float s2p = __builtin_amdgcn_sinf(p[4] * INV_PI), c2p = __builtin_amdgcn_cosf(p[4] * INV_PI);
    float s2t = __builtin_amdgcn_sinf(t[4] * INV_PI), c2t = __builtin_amdgcn_cosf(t[4] * INV_PI);
    float hp = 0.5f * (ap + bp), qp = 0.5f * (ap - bp);
    float ht = 0.5f * (at + bt), qt = 0.5f * (at - bt);
    float p00 = hp + qp * c2p, p11 = hp - qp * c2p, p01 = qp * s2p;
    float t00 = ht + qt * c2t, t11 = ht - qt * c2t, t01 = qt * s2t;
    float dp = ap * bp, dt = at * bt;
    float inv_dt = fast_rcp(dt);
    float dx = p[0] - t[0], dy = p[1] - t[1];
    float term1 = (dx * dx * t11 - 2.0f * dx * dy * t01 + dy * dy * t00) * inv_dt;
    float tr    = (t11 * p00 + t00 * p11 - 2.0f * t01 * p01) * inv_dt;
    float logterm = LN2 * fast_log2(dt * fast_rcp(dp));
    float dis = term1 + tr + logterm - 2.0f;
    float kl  = fmaxf(dis, 1e-6f);
    return 1.0f - fast_rcp(TAU_CONST + LN2 * fast_log2(1.0f + kl));
}

// Stage one wave-tile (256 rows) of pred+target into this wave's LDS buffer
// via async global->LDS DMA. LDS dest is wave-uniform base + lane*16.
__device__ __forceinline__ void stage_tile(const char* predB, const char* targB,
                                           int t, float* buf, int lane) {
    const char* gp = predB + (size_t)t * 5120 + (size_t)lane * 16;
    const char* gt = targB + (size_t)t * 5120 + (size_t)lane * 16;
    float* lp = buf;          // pred image: floats [0..1279]
    float* lt = buf + 1280;   // targ image: floats [1280..2559]
#pragma unroll
    for (int i = 0; i < 5; ++i) {
        __builtin_amdgcn_global_load_lds((const __attribute__((address_space(1))) void*)(gp + i * 1024),
                                         (__attribute__((address_space(3))) void*)(lp + i * 256), 16, 0, 0);
        __builtin_amdgcn_global_load_lds((const __attribute__((address_space(1))) void*)(gt + i * 1024),
                                         (__attribute__((address_space(3))) void*)(lt + i * 256), 16, 0, 0);
    }
}

// Persistent, wave-private double-buffered LDS streaming. No __syncthreads:
// each wave owns its tiles, overlap enforced with manual s_waitcnt vmcnt(10)
// (10 = the DMA insts just issued for the next tile; in-order vmcnt retirement
// guarantees the current tile's DMAs and older stores are drained).
__global__ void __launch_bounds__(BLOCK) gdloss_ldsdma_kernel(const char* __restrict__ predB,
                                                              const char* __restrict__ targB,
                                                              vfloat4* __restrict__ out4,
                                                              int ntiles) {
    __shared__ __align__(16) float sbuf[WPB][2][2560];   // [wave][buf][pred|targ] = 40 KB
    const int lane = threadIdx.x & 63;
    const int w    = threadIdx.x >> 6;
    const int gw   = blockIdx.x * WPB + w;
    const int stride = gridDim.x * WPB;

    int t = gw;
    if (t >= ntiles) return;                 // wave-uniform
    stage_tile(predB, targB, t, &sbuf[w][0][0], lane);
    int cur = 0;
    while (true) {
        const int tn = t + stride;
        const bool more = (tn < ntiles);
        if (more) {
            stage_tile(predB, targB, tn, &sbuf[w][cur ^ 1][0], lane);
            asm volatile("s_waitcnt vmcnt(10)" ::: "memory");
        } else {
            asm volatile("s_waitcnt vmcnt(0)" ::: "memory");
        }
        const float* P = &sbuf[w][cur][0]    + lane * 20;   // 4 rows, 80B-aligned
        const float* T = &sbuf[w][cur][1280] + lane * 20;
        vfloat4 o;
        o.x = kld_row(P + 0,  T + 0);
        o.y = kld_row(P + 5,  T + 5);
        o.z = kld_row(P + 10, T + 10);
        o.w = kld_row(P + 15, T + 15);
        out4[(size_t)t * 64 + lane] = o;
        if (!more) break;
        t = tn; cur ^= 1;
    }
}

// Generic tail for rows not covered by full 256-row tiles (none at N=4M).
__global__ void gdloss_tail_kernel(const float* __restrict__ pred,
                                   const float* __restrict__ target,
                                   float* __restrict__ out, int start, int n) {
    int i = start + blockIdx.x * blockDim.x + threadIdx.x;
    if (i >= n) return;
    float p[5], t[5];
#pragma unroll
    for (int k = 0; k < 5; ++k) { p[k] = pred[5 * i + k]; t[k] = target[5 * i + k]; }
    out[i] = kld_row(p, t);
}

extern "C" void kernel_launch(void* const* d_in, const int* in_sizes, int n_in,
                              void* d_out, int out_size, void* d_ws, size_t ws_size,
                              hipStream_t stream) {
    const float* pred   = (const float*)d_in[0];
    const float* target = (const float*)d_in[1];
    float* out = (float*)d_out;
    const int n = in_sizes[0] / 5;            // rows
    const int ntiles = n / ROWS_PER_TILE;     // full 256-row wave-tiles
    if (ntiles > 0) {
        int blocks = (ntiles + WPB - 1) / WPB;
        if (blocks > NBLOCKS) blocks = NBLOCKS;
        gdloss_ldsdma_kernel<<<blocks, BLOCK, 0, stream>>>((const char*)pred,
                                                           (const char*)target,
                                                           (vfloat4*)out, ntiles);
    }
    const int done = ntiles * ROWS_PER_TILE;
    if (n - done > 0) {
        int rem = n - done;
        gdloss_tail_kernel<<<(rem + 255) / 256, 256, 0, stream>>>(pred, target, out, done, n);
    }
}